// Round 11
// baseline (334.573 us; speedup 1.0000x reference)
//
#include <hip/hip_runtime.h>
#include <hip/hip_bf16.h>

#define NODES 50000
#define NEDGE 800000
#define CH 128          // all of IN/HID/OUT
#define NEG_SLOPE 0.2f
#define SCAN_CHUNK 2048
#define NBLK ((NODES + SCAN_CHUNK - 1) / SCAN_CHUNK)   // 25
#define NINF -1.0e30f
#define LOG2E 1.44269504088896340736f
#define RESCALE_THR 8.0f
#define NSLICE 400
#define SSLICE (NEDGE / NSLICE)       // 2000 edges per slice (scatter, 512 thr)
#define HSLICE 4000                   // edges per slice (hist, 512 thr)
#define NHS (NEDGE / HSLICE)          // 200 hist slices
#define ZB ((NODES + 255) / 256)      // 196 zero-blocks
#define GR 64
#define GGC ((NODES + GR - 1) / GR)   // 782 full-gemm blocks
#define GB 391                        // blocks per half-GEMM
#define HROWS (GB * GR)               // 25024 rows in half A
#define NPB ((NODES - HROWS) / 8)     // 3122 node-role blocks (8 nodes/block)
#define LDP 136   // padded row stride in shorts (272 B)

typedef short short8 __attribute__((ext_vector_type(8)));
typedef float f32x4 __attribute__((ext_vector_type(4)));
typedef float f32x2 __attribute__((ext_vector_type(2)));

__device__ __forceinline__ unsigned fbits(float f) {
    union { float f; unsigned u; } v; v.f = f; return v.u;
}
__device__ __forceinline__ float asf(unsigned u) {
    union { float f; unsigned u; } v; v.u = u; return v.f;
}
// fp32 -> bf16 (RNE)
__device__ __forceinline__ unsigned short f2bf(float f) {
    unsigned u = fbits(f);
    unsigned r = u + 0x7fff + ((u >> 16) & 1);
    return (unsigned short)(r >> 16);
}
__device__ __forceinline__ float bf2f(unsigned short h) {
    return asf(((unsigned)h) << 16);
}
// 8 bf16 (as uint4) -> 4 x float2 (packed-math friendly)
__device__ __forceinline__ void bf8cvt2(uint4 u, f32x2* f) {
    f[0] = (f32x2){asf(u.x << 16), asf(u.x & 0xFFFF0000u)};
    f[1] = (f32x2){asf(u.y << 16), asf(u.y & 0xFFFF0000u)};
    f[2] = (f32x2){asf(u.z << 16), asf(u.z & 0xFFFF0000u)};
    f[3] = (f32x2){asf(u.w << 16), asf(u.w & 0xFFFF0000u)};
}
// dst-range set for XCD-partitioned CSR build
__device__ __forceinline__ int dset(int dst) {
    return (int)(((unsigned)dst * 8u) / 50000u);   // exact partition of [0,50000)
}

// ---------------------------------------------------------------------------
// prep: zero histogram + detect edge dtype + W->bf16 hi/lo transpose, fused.
// ---------------------------------------------------------------------------
__global__ __launch_bounds__(256) void prep_kernel(const void* idx, int* flag,
                                                   int* cnt,
                                                   const float* __restrict__ W0,
                                                   const float* __restrict__ W1,
                                                   const float* __restrict__ W2,
                                                   const float* __restrict__ W3,
                                                   unsigned short* __restrict__ wbase) {
    int b = (int)blockIdx.x;
    if (b < ZB) {
        int t = b * 256 + (int)threadIdx.x;
        if (t < NODES) cnt[t] = 0;
        if (b == 0 && threadIdx.x < 64) {
            const int* w = (const int*)idx;
            int nz = (w[2 * threadIdx.x + 1] != 0) ? 1 : 0;
            unsigned long long bal = __ballot(nz);
            if (threadIdx.x == 0) *flag = (bal == 0ull) ? 1 : 0;
        }
        return;
    }
    int wb = b - ZB;                               // 0..255
    int which = wb >> 6;
    const float* W = (which == 0) ? W0 : (which == 1) ? W1 : (which == 2) ? W2 : W3;
    unsigned short* hiT = wbase + (size_t)which * 32768;
    unsigned short* loT = hiT + 16384;
    int i = (wb & 63) * 256 + (int)threadIdx.x;    // 0..16383
    int k = i >> 7, n = i & 127;
    float f = W[i];
    unsigned short h = f2bf(f);
    unsigned short l = f2bf(f - bf2f(h));
    hiT[n * CH + k] = h;
    loT[n * CH + k] = l;
}

__global__ __launch_bounds__(256) void scan1_kernel(const int* __restrict__ cnt,
                                                    int* __restrict__ bsum) {
    int base = blockIdx.x * SCAN_CHUNK + (int)threadIdx.x * 8;
    int s = 0;
    #pragma unroll
    for (int k = 0; k < 8; ++k) {
        int i = base + k;
        s += (i < NODES) ? cnt[i] : 0;
    }
    #pragma unroll
    for (int m = 1; m < 64; m <<= 1) s += __shfl_xor(s, m);
    __shared__ int ws[4];
    if ((threadIdx.x & 63) == 0) ws[threadIdx.x >> 6] = s;
    __syncthreads();
    if (threadIdx.x == 0) bsum[blockIdx.x] = ws[0] + ws[1] + ws[2] + ws[3];
}

__global__ __launch_bounds__(256) void scan3_kernel(const int* __restrict__ cnt,
                                                    const int* __restrict__ bsum,
                                                    int* __restrict__ offs,
                                                    int* __restrict__ cursor) {
    int tid = (int)threadIdx.x;
    int bpre = 0;
    #pragma unroll
    for (int b = 0; b < NBLK; ++b) bpre += (b < (int)blockIdx.x) ? bsum[b] : 0;

    int base = blockIdx.x * SCAN_CHUNK + tid * 8;
    int v[8];
    int s = 0;
    #pragma unroll
    for (int k = 0; k < 8; ++k) {
        int i = base + k;
        v[k] = (i < NODES) ? cnt[i] : 0;
        s += v[k];
    }
    int lane = tid & 63;
    int incl = s;
    #pragma unroll
    for (int m = 1; m < 64; m <<= 1) {
        int t = __shfl_up(incl, m);
        if (lane >= m) incl += t;
    }
    __shared__ int wtot[4];
    if (lane == 63) wtot[tid >> 6] = incl;
    __syncthreads();
    int w = tid >> 6;
    int wbase = 0;
    #pragma unroll
    for (int k = 0; k < 4; ++k) wbase += (k < w) ? wtot[k] : 0;
    int excl = bpre + wbase + (incl - s);
    #pragma unroll
    for (int k = 0; k < 8; ++k) {
        int i = base + k;
        if (i < NODES) { offs[i] = excl; cursor[i] = excl; }
        excl += v[k];
    }
    if (blockIdx.x == 0 && tid == 0) offs[NODES] = NEDGE;
}

// ---------------------------------------------------------------------------
// Shared layer-1 GEMM role body (fp32 input, split-bf16 MFMA).
// ---------------------------------------------------------------------------
__device__ __forceinline__ void gemm1_role(
        int r0, int tid,
        unsigned short (*xh)[LDP], unsigned short (*xlo)[LDP],
        const float* __restrict__ X,
        const unsigned short* __restrict__ whTl, const unsigned short* __restrict__ wlTl,
        const unsigned short* __restrict__ whTr, const unsigned short* __restrict__ wlTr,
        const float* __restrict__ bl, const float* __restrict__ br,
        unsigned short* __restrict__ Ylb, float* __restrict__ Yr, int nrows) {
    // stage X tile: fp32 -> hi/lo bf16 (truncation split), packed
    {
        int row = tid >> 3;              // 0..63
        int c0 = (tid & 7) * 16;         // col start, 16 cols per thread
        const float* src = X + (size_t)(r0 + row) * CH + c0;
        bool valid = (r0 + row) < nrows;
        #pragma unroll
        for (int j = 0; j < 16; j += 4) {
            float4 v = valid ? *(const float4*)(src + j)
                             : make_float4(0.f, 0.f, 0.f, 0.f);
            unsigned ux = fbits(v.x), uy = fbits(v.y);
            unsigned uz = fbits(v.z), uw = fbits(v.w);
            unsigned hx = ux & 0xFFFF0000u, hy = uy & 0xFFFF0000u;
            unsigned hz = uz & 0xFFFF0000u, hw = uw & 0xFFFF0000u;
            uint2 hp;
            hp.x = (ux >> 16) | hy;
            hp.y = (uz >> 16) | hw;
            float lx = v.x - asf(hx), ly = v.y - asf(hy);
            float lz = v.z - asf(hz), lw = v.w - asf(hw);
            uint2 lp;
            lp.x = (fbits(lx) >> 16) | (fbits(ly) & 0xFFFF0000u);
            lp.y = (fbits(lz) >> 16) | (fbits(lw) & 0xFFFF0000u);
            *(uint2*)&xh[row][c0 + j]  = hp;
            *(uint2*)&xlo[row][c0 + j] = lp;
        }
    }
    __syncthreads();

    int wave = tid >> 6;      // 0..7: n-eighth (32 cols each)
    int lane = tid & 63;
    int l15 = lane & 15, q = lane >> 4;

    f32x4 acc[4][2];
    #pragma unroll
    for (int mt = 0; mt < 4; ++mt)
        #pragma unroll
        for (int nt = 0; nt < 2; ++nt) acc[mt][nt] = (f32x4)0.f;

    const unsigned short* bhp[2];
    const unsigned short* blp_[2];
    int ncol[2];
    #pragma unroll
    for (int nt = 0; nt < 2; ++nt) {
        int n = (wave * 2 + nt) * 16 + l15;       // 0..255
        ncol[nt] = n;
        int nn = n & 127;
        bhp[nt]  = ((n < CH) ? whTl : whTr) + (size_t)nn * CH;
        blp_[nt] = ((n < CH) ? wlTl : wlTr) + (size_t)nn * CH;
    }

    for (int kt = 0; kt < 4; ++kt) {
        int kofs = kt * 32 + q * 8;
        short8 ah[4], al[4];
        #pragma unroll
        for (int mt = 0; mt < 4; ++mt) {
            ah[mt] = *(const short8*)&xh[mt * 16 + l15][kofs];
            al[mt] = *(const short8*)&xlo[mt * 16 + l15][kofs];
        }
        #pragma unroll
        for (int nt = 0; nt < 2; ++nt) {
            short8 bh8 = *(const short8*)(bhp[nt] + kofs);
            short8 bl8 = *(const short8*)(blp_[nt] + kofs);
            #pragma unroll
            for (int mt = 0; mt < 4; ++mt) {
                acc[mt][nt] = __builtin_amdgcn_mfma_f32_16x16x32_bf16(
                                  ah[mt], bh8, acc[mt][nt], 0, 0, 0);
                acc[mt][nt] = __builtin_amdgcn_mfma_f32_16x16x32_bf16(
                                  al[mt], bh8, acc[mt][nt], 0, 0, 0);
                acc[mt][nt] = __builtin_amdgcn_mfma_f32_16x16x32_bf16(
                                  ah[mt], bl8, acc[mt][nt], 0, 0, 0);
            }
        }
    }

    // epilogue: C/D layout col=lane&15, row=q*4+reg
    #pragma unroll
    for (int nt = 0; nt < 2; ++nt) {
        int n = ncol[nt];
        int nc = n & 127;
        if (n < CH) {
            float bv = bl[nc];
            #pragma unroll
            for (int mt = 0; mt < 4; ++mt)
                #pragma unroll
                for (int reg = 0; reg < 4; ++reg) {
                    int row = r0 + mt * 16 + q * 4 + reg;
                    if (row < nrows)
                        Ylb[(size_t)row * CH + nc] = f2bf(acc[mt][nt][reg] + bv);
                }
        } else {
            float bv = br[nc];
            #pragma unroll
            for (int mt = 0; mt < 4; ++mt)
                #pragma unroll
                for (int reg = 0; reg < 4; ++reg) {
                    int row = r0 + mt * 16 + q * 4 + reg;
                    if (row < nrows)
                        Yr[(size_t)row * CH + nc] = acc[mt][nt][reg] + bv;
                }
        }
    }
}

// ---------------------------------------------------------------------------
// Shared layer-2 GEMM role body (input pre-split bf16 hi/lo planes).
// NOTE: no __restrict__ on pointers (aliased across roles in fused kernels).
// ---------------------------------------------------------------------------
__device__ __forceinline__ void gemm_pl_role(
        int r0, int tid,
        unsigned short (*xh)[LDP], unsigned short (*xlo)[LDP],
        const unsigned short* Ah, const unsigned short* Al,
        const unsigned short* __restrict__ whTl, const unsigned short* __restrict__ wlTl,
        const unsigned short* __restrict__ whTr, const unsigned short* __restrict__ wlTr,
        const float* __restrict__ bl, const float* __restrict__ br,
        unsigned short* Ylb, float* Yr, int nrows) {
    // stage hi/lo planes: coalesced 8 threads/row x 32B each
    {
        int row = tid >> 3;              // 0..63
        int c0 = (tid & 7) * 16;         // 16 u16 per thread
        int gr = r0 + row;
        if (gr > nrows - 1) gr = nrows - 1;   // clamp: dup row, stores guarded
        const uint4* ph = (const uint4*)(Ah + (size_t)gr * CH + c0);
        const uint4* pl = (const uint4*)(Al + (size_t)gr * CH + c0);
        uint4 h0 = ph[0], h1 = ph[1];
        uint4 l0 = pl[0], l1 = pl[1];
        *(uint4*)&xh[row][c0]      = h0;
        *(uint4*)&xh[row][c0 + 8]  = h1;
        *(uint4*)&xlo[row][c0]     = l0;
        *(uint4*)&xlo[row][c0 + 8] = l1;
    }
    __syncthreads();

    int wave = tid >> 6;      // 0..7
    int lane = tid & 63;
    int l15 = lane & 15, q = lane >> 4;

    f32x4 acc[4][2];
    #pragma unroll
    for (int mt = 0; mt < 4; ++mt)
        #pragma unroll
        for (int nt = 0; nt < 2; ++nt) acc[mt][nt] = (f32x4)0.f;

    const unsigned short* bhp[2];
    const unsigned short* blp_[2];
    int ncol[2];
    #pragma unroll
    for (int nt = 0; nt < 2; ++nt) {
        int n = (wave * 2 + nt) * 16 + l15;
        ncol[nt] = n;
        int nn = n & 127;
        bhp[nt]  = ((n < CH) ? whTl : whTr) + (size_t)nn * CH;
        blp_[nt] = ((n < CH) ? wlTl : wlTr) + (size_t)nn * CH;
    }

    for (int kt = 0; kt < 4; ++kt) {
        int kofs = kt * 32 + q * 8;
        short8 ah[4], al[4];
        #pragma unroll
        for (int mt = 0; mt < 4; ++mt) {
            ah[mt] = *(const short8*)&xh[mt * 16 + l15][kofs];
            al[mt] = *(const short8*)&xlo[mt * 16 + l15][kofs];
        }
        #pragma unroll
        for (int nt = 0; nt < 2; ++nt) {
            short8 bh8 = *(const short8*)(bhp[nt] + kofs);
            short8 bl8 = *(const short8*)(blp_[nt] + kofs);
            #pragma unroll
            for (int mt = 0; mt < 4; ++mt) {
                acc[mt][nt] = __builtin_amdgcn_mfma_f32_16x16x32_bf16(
                                  ah[mt], bh8, acc[mt][nt], 0, 0, 0);
                acc[mt][nt] = __builtin_amdgcn_mfma_f32_16x16x32_bf16(
                                  al[mt], bh8, acc[mt][nt], 0, 0, 0);
                acc[mt][nt] = __builtin_amdgcn_mfma_f32_16x16x32_bf16(
                                  ah[mt], bl8, acc[mt][nt], 0, 0, 0);
            }
        }
    }

    #pragma unroll
    for (int nt = 0; nt < 2; ++nt) {
        int n = ncol[nt];
        int nc = n & 127;
        if (n < CH) {
            float bv = bl[nc];
            #pragma unroll
            for (int mt = 0; mt < 4; ++mt)
                #pragma unroll
                for (int reg = 0; reg < 4; ++reg) {
                    int row = r0 + mt * 16 + q * 4 + reg;
                    if (row < nrows)
                        Ylb[(size_t)row * CH + nc] = f2bf(acc[mt][nt][reg] + bv);
                }
        } else {
            float bv = br[nc];
            #pragma unroll
            for (int mt = 0; mt < 4; ++mt)
                #pragma unroll
                for (int reg = 0; reg < 4; ++reg) {
                    int row = r0 + mt * 16 + q * 4 + reg;
                    if (row < nrows)
                        Yr[(size_t)row * CH + nc] = acc[mt][nt][reg] + bv;
                }
        }
    }
}

// ---------------------------------------------------------------------------
// Shared node-pass body (R2 form): one node per wave, 16 lanes per edge row,
// 4 edges in flight (one per quarter-wave). Defer-max online softmax (T13).
// NOTE: no __restrict__ on xlb/xr/outh/outl (aliased across roles in fused).
// ---------------------------------------------------------------------------
template <int HEADS, bool RELU, bool SPLITOUT>
__device__ __forceinline__ void node_body(
        int i, int lane,
        const unsigned short* xlb, const float* xr,
        const float* __restrict__ att, const float* __restrict__ bias,
        const int* __restrict__ offs, const int* __restrict__ srcs,
        float* outf, unsigned short* outh, unsigned short* outl) {
    constexpr int GL = (CH / HEADS) / 8;     // lanes per head group: 4 or 16
    int g = lane >> 4;                       // quarter 0..3
    int l16 = lane & 15;
    int c0 = l16 * 8;                        // this lane's 8 channels

    f32x2 r2[4], a2[4], s2[4];
    {
        const float4* xrp = (const float4*)(xr + (size_t)i * CH + c0);
        float4 r0 = xrp[0], r1 = xrp[1];
        r2[0] = (f32x2){r0.x, r0.y}; r2[1] = (f32x2){r0.z, r0.w};
        r2[2] = (f32x2){r1.x, r1.y}; r2[3] = (f32x2){r1.z, r1.w};
        const float4* atp = (const float4*)(att + c0);
        float4 a0 = atp[0], a1 = atp[1];
        a2[0] = (f32x2){a0.x, a0.y} * LOG2E; a2[1] = (f32x2){a0.z, a0.w} * LOG2E;
        a2[2] = (f32x2){a1.x, a1.y} * LOG2E; a2[3] = (f32x2){a1.z, a1.w} * LOG2E;
    }
    // self row (bf16)
    uint4 us = *(const uint4*)(xlb + (size_t)i * CH + c0);
    bf8cvt2(us, s2);

    f32x2 td = (f32x2)0.f;
    #pragma unroll
    for (int k = 0; k < 4; ++k) {
        f32x2 z = s2[k] + r2[k];
        f32x2 l = __builtin_elementwise_max(z, z * NEG_SLOPE);
        td += l * a2[k];
    }
    float ts = td.x + td.y;
    #pragma unroll
    for (int msk = 1; msk < GL; msk <<= 1) ts += __shfl_xor(ts, msk);

    // defer-max init: every quarter anchors at the self logit (finite, and
    // identical across quarters since all quarters load the same self row).
    float m = ts;
    float d = (g == 0) ? 1.f : 0.f;
    f32x2 acc2[4];
    #pragma unroll
    for (int k = 0; k < 4; ++k) acc2[k] = (g == 0) ? s2[k] : (f32x2)0.f;

    int beg = offs[i], end = offs[i + 1];
    int deg = end - beg;
    int iters = (deg + 3) >> 2;
    if (iters > 0) {
        int last = end - 1;
        int e = beg + g;
        int si = srcs[min(e, last)];
        uint4 u = *(const uint4*)(xlb + (size_t)si * CH + c0);

        for (int it = 0; it < iters; ++it, e += 4) {
            bool valid = e < end;
            // prefetch next edge for this quarter (clamped: own segment only)
            int sn = srcs[min(e + 4, last)];
            uint4 un = *(const uint4*)(xlb + (size_t)sn * CH + c0);

            f32x2 f2[4];
            bf8cvt2(u, f2);
            f32x2 td2 = (f32x2)0.f;
            #pragma unroll
            for (int k = 0; k < 4; ++k) {
                f32x2 z = f2[k] + r2[k];
                f32x2 l = __builtin_elementwise_max(z, z * NEG_SLOPE);
                td2 += l * a2[k];
            }
            float t = td2.x + td2.y;
            #pragma unroll
            for (int msk = 1; msk < GL; msk <<= 1) t += __shfl_xor(t, msk);
            t = valid ? t : NINF;   // exp2(NINF - m) underflows to 0 in HW

            if (__any(t > m + RESCALE_THR)) {
                // exact rescale path (rare)
                float nm = fmaxf(m, t);
                float sc = exp2f(m - nm);
                float p  = exp2f(t - nm);
                d = d * sc + p;
                #pragma unroll
                for (int k = 0; k < 4; ++k) acc2[k] = acc2[k] * sc + f2[k] * p;
                m = nm;
            } else {
                // deferred path: p <= 2^THR, no rescale of the accumulator
                float p = exp2f(t - m);
                d += p;
                #pragma unroll
                for (int k = 0; k < 4; ++k) acc2[k] += f2[k] * p;
            }
            u = un;
        }
    }

    // merge the 4 quarter-wave states (butterfly: all lanes converge)
    #pragma unroll
    for (int msk = 16; msk <= 32; msk <<= 1) {
        float mo  = __shfl_xor(m, msk);
        float dof = __shfl_xor(d, msk);
        float nm = fmaxf(m, mo);
        float s0 = exp2f(m - nm), s1 = exp2f(mo - nm);
        d = d * s0 + dof * s1;
        #pragma unroll
        for (int k = 0; k < 4; ++k) {
            f32x2 ao;
            ao.x = __shfl_xor(acc2[k].x, msk);
            ao.y = __shfl_xor(acc2[k].y, msk);
            acc2[k] = acc2[k] * s0 + ao * s1;
        }
        m = nm;
    }

    if (g == 0) {
        float inv = 1.0f / d;
        const float4* bp = (const float4*)(bias + c0);
        float4 b0 = bp[0], b1 = bp[1];
        float bb[8] = {b0.x, b0.y, b0.z, b0.w, b1.x, b1.y, b1.z, b1.w};
        float o[8];
        #pragma unroll
        for (int k = 0; k < 4; ++k) {
            o[2*k]   = acc2[k].x * inv + bb[2*k];
            o[2*k+1] = acc2[k].y * inv + bb[2*k+1];
        }
        #pragma unroll
        for (int c = 0; c < 8; ++c)
            if (RELU) o[c] = fmaxf(o[c], 0.f);
        if (SPLITOUT) {
            unsigned hu[8];
            float lo[8];
            #pragma unroll
            for (int c = 0; c < 8; ++c) {
                hu[c] = fbits(o[c]) & 0xFFFF0000u;
                lo[c] = o[c] - asf(hu[c]);
            }
            uint4 ph, pl;
            ph.x = (hu[0] >> 16) | hu[1];  ph.y = (hu[2] >> 16) | hu[3];
            ph.z = (hu[4] >> 16) | hu[5];  ph.w = (hu[6] >> 16) | hu[7];
            pl.x = (fbits(lo[0]) >> 16) | (fbits(lo[1]) & 0xFFFF0000u);
            pl.y = (fbits(lo[2]) >> 16) | (fbits(lo[3]) & 0xFFFF0000u);
            pl.z = (fbits(lo[4]) >> 16) | (fbits(lo[5]) & 0xFFFF0000u);
            pl.w = (fbits(lo[6]) >> 16) | (fbits(lo[7]) & 0xFFFF0000u);
            *(uint4*)(outh + (size_t)i * CH + c0) = ph;
            *(uint4*)(outl + (size_t)i * CH + c0) = pl;
        } else {
            float4 w0 = make_float4(o[0], o[1], o[2], o[3]);
            float4 w1 = make_float4(o[4], o[5], o[6], o[7]);
            float4* op = (float4*)(outf + (size_t)i * CH + c0);
            op[0] = w0; op[1] = w1;
        }
    }
}

// ---------------------------------------------------------------------------
// Fused kernel A: GEMM half A (rows [0, HROWS)) + edge HISTOGRAM passenger.
// ---------------------------------------------------------------------------
__global__ __launch_bounds__(512) void gemm1a_hist(
        const float* __restrict__ X,
        const unsigned short* __restrict__ whTl, const unsigned short* __restrict__ wlTl,
        const unsigned short* __restrict__ whTr, const unsigned short* __restrict__ wlTr,
        const float* __restrict__ bl, const float* __restrict__ br,
        unsigned short* __restrict__ Ylb, float* __restrict__ Yr, int nrows,
        const void* idx, const int* flag, int* cnt) {
    __shared__ unsigned short xh[GR][LDP];
    __shared__ unsigned short xlo[GR][LDP];

    if (blockIdx.x >= GB) {
        // ---- histogram role: 200 slices x 4000 edges, 512 threads ----
        int set = (int)blockIdx.x & 7;
        int slice = ((int)blockIdx.x - GB) >> 3;    // 0..NHS-1
        int base = slice * HSLICE;
        int endE = base + HSLICE;
        int i64 = *flag;
        const int* w = (const int*)idx;
        for (int e = base + (int)threadIdx.x; e < endE; e += 512) {
            int dst = i64 ? w[2 * (NEDGE + e)] : w[NEDGE + e];
            if (dset(dst) == set) atomicAdd(&cnt[dst], 1);
        }
        return;
    }
    gemm1_role(blockIdx.x * GR, (int)threadIdx.x, xh, xlo,
               X, whTl, wlTl, whTr, wlTr, bl, br, Ylb, Yr, nrows);
}

// ---------------------------------------------------------------------------
// Fused kernel B: GEMM half B (rows [HROWS, NODES)) + edge SCATTER passenger.
// ---------------------------------------------------------------------------
__global__ __launch_bounds__(512) void gemm1b_scatter(
        const float* __restrict__ X,
        const unsigned short* __restrict__ whTl, const unsigned short* __restrict__ wlTl,
        const unsigned short* __restrict__ whTr, const unsigned short* __restrict__ wlTr,
        const float* __restrict__ bl, const float* __restrict__ br,
        unsigned short* __restrict__ Ylb, float* __restrict__ Yr, int nrows,
        const void* idx, const int* flag, int* cursor, int* __restrict__ srcs) {
    __shared__ unsigned short xh[GR][LDP];
    __shared__ unsigned short xlo[GR][LDP];

    if (blockIdx.x >= GB) {
        // ---- scatter role: 400 slices x 2000 edges, 512 threads ----
        int set = (int)blockIdx.x & 7;
        int slice = ((int)blockIdx.x - GB) >> 3;    // 0..NSLICE-1
        int base = slice * SSLICE;
        int endE = base + SSLICE;
        int i64 = *flag;
        const int* w = (const int*)idx;
        for (int e = base + (int)threadIdx.x; e < endE; e += 512) {
            int dst = i64 ? w[2 * (NEDGE + e)] : w[NEDGE + e];
            if (dset(dst) == set) {
                int src = i64 ? w[2 * e] : w[e];
                int pos = atomicAdd(&cursor[dst], 1);
                srcs[pos] = src;
            }
        }
        return;
    }
    gemm1_role(HROWS + blockIdx.x * GR, (int)threadIdx.x, xh, xlo,
               X, whTl, wlTl, whTr, wlTr, bl, br, Ylb, Yr, nrows);
}

// ---------------------------------------------------------------------------
// Standalone layer-2 GEMM with row offset (r0base): serial path uses
// (0, GGC blocks); overlap path uses (HROWS, GB blocks) for half B.
// ---------------------------------------------------------------------------
__global__ __launch_bounds__(512) void gemm_pl_kernel(
        const unsigned short* Ah, const unsigned short* Al,
        const unsigned short* __restrict__ whTl, const unsigned short* __restrict__ wlTl,
        const unsigned short* __restrict__ whTr, const unsigned short* __restrict__ wlTr,
        const float* __restrict__ bl, const float* __restrict__ br,
        unsigned short* Ylb, float* Yr, int nrows, int r0base) {
    __shared__ unsigned short xh[GR][LDP];
    __shared__ unsigned short xlo[GR][LDP];
    gemm_pl_role(r0base + (int)blockIdx.x * GR, (int)threadIdx.x, xh, xlo,
                 Ah, Al, whTl, wlTl, whTr, wlTr, bl, br, Ylb, Yr, nrows);
}

// ---------------------------------------------------------------------------
// Standalone node pass (4 nodes/block of 256 threads). Node i = blockIdx*4+wave.
// ---------------------------------------------------------------------------
template <int HEADS, bool RELU, bool SPLITOUT>
__global__ __launch_bounds__(256) void node_pass(
        const unsigned short* xlb, const float* xr,
        const float* __restrict__ att, const float* __restrict__ bias,
        const int* __restrict__ offs, const int* __restrict__ srcs,
        float* outf, unsigned short* outh, unsigned short* outl) {
    int wave = (int)threadIdx.x >> 6;
    int i = blockIdx.x * 4 + wave;
    int lane = (int)threadIdx.x & 63;
    node_body<HEADS, RELU, SPLITOUT>(i, lane, xlb, xr, att, bias, offs, srcs,
                                     outf, outh, outl);
}

// ---------------------------------------------------------------------------
// OVERLAP kernel: layer-2 GEMM half A (rows [0,HROWS), reads hbh/hbl written
// by np1a, writes xlb2/xr) runs concurrently with layer-1 node pass for nodes
// [HROWS, NODES) (reads layer-1 xlb everywhere + xr rows >= HROWS, writes
// hbh/hbl rows >= HROWS). Row-disjointness proof in launcher comments.
// 512 threads; node role = 8 nodes/block.
// ---------------------------------------------------------------------------
__global__ __launch_bounds__(512) void np1b_gplA(
        // gemm role
        const unsigned short* hbh, const unsigned short* hbl,
        const unsigned short* __restrict__ w2lh, const unsigned short* __restrict__ w2ll,
        const unsigned short* __restrict__ w2rh, const unsigned short* __restrict__ w2rl,
        const float* __restrict__ b2l, const float* __restrict__ b2r,
        unsigned short* xlb2, float* xr,
        // node role
        const unsigned short* xlb1,
        const float* __restrict__ att1, const float* __restrict__ bias1,
        const int* __restrict__ offs, const int* __restrict__ srcs) {
    __shared__ unsigned short xh[GR][LDP];
    __shared__ unsigned short xlo[GR][LDP];

    if (blockIdx.x < GB) {
        // gemm_pl half A: rows [0, HROWS)
        gemm_pl_role((int)blockIdx.x * GR, (int)threadIdx.x, xh, xlo,
                     hbh, hbl, w2lh, w2ll, w2rh, w2rl, b2l, b2r,
                     xlb2, xr, NODES);
        return;
    }
    // node role: layer-1 pass, nodes [HROWS, NODES), 8 nodes per block
    int wave = (int)threadIdx.x >> 6;                 // 0..7
    int i = HROWS + ((int)blockIdx.x - GB) * 8 + wave;
    int lane = (int)threadIdx.x & 63;
    node_body<4, true, true>(i, lane, xlb1, xr, att1, bias1, offs, srcs,
                             nullptr, (unsigned short*)hbh, (unsigned short*)hbl);
}

// ---------------------------------------------------------------------------
extern "C" void kernel_launch(void* const* d_in, const int* in_sizes, int n_in,
                              void* d_out, int out_size, void* d_ws, size_t ws_size,
                              hipStream_t stream) {
    const float* x     = (const float*)d_in[0];
    const void*  eidx  = d_in[1];
    const float* W1l   = (const float*)d_in[2];
    const float* b1l   = (const float*)d_in[3];
    const float* W1r   = (const float*)d_in[4];
    const float* b1r   = (const float*)d_in[5];
    const float* att1  = (const float*)d_in[6];
    const float* bias1 = (const float*)d_in[7];
    const float* W2l   = (const float*)d_in[8];
    const float* b2l   = (const float*)d_in[9];
    const float* W2r   = (const float*)d_in[10];
    const float* b2r   = (const float*)d_in[11];
    const float* att2  = (const float*)d_in[12];
    const float* bias2 = (const float*)d_in[13];
    float* out = (float*)d_out;

    // workspace layout
    unsigned short* xlb = (unsigned short*)d_ws;        // N*128 bf16 (attn side)
    float* xr = (float*)(xlb + (size_t)NODES * CH);     // N*128 fp32 (dst side)
    unsigned short* hbh = (unsigned short*)(xr + (size_t)NODES * CH); // N*128 u16
    unsigned short* hbl = hbh + (size_t)NODES * CH;     // N*128 u16
    int* offs   = (int*)(hbl + (size_t)NODES * CH);     // N+1
    int* cnt    = offs + (NODES + 1);                   // N
    int* cursor = cnt + NODES;                          // N
    int* srcs   = cursor + NODES;                       // E
    int* flag   = srcs + NEDGE;                         // 1
    int* bsum   = flag + 1;                             // NBLK
    unsigned short* wbuf =
        (unsigned short*)(((uintptr_t)(bsum + NBLK) + 15) & ~(uintptr_t)15);
    unsigned short* w1lh = wbuf;              unsigned short* w1ll = wbuf + 16384;
    unsigned short* w1rh = wbuf + 32768;      unsigned short* w1rl = wbuf + 49152;
    unsigned short* w2lh = wbuf + 65536;      unsigned short* w2ll = wbuf + 81920;
    unsigned short* w2rh = wbuf + 98304;      unsigned short* w2rl = wbuf + 114688;
    // layer-2 attn-side buffer for the overlap path (extra 12.8 MB)
    unsigned short* xlb2 = wbuf + 131072;
    size_t need = (size_t)((char*)(xlb2 + (size_t)NODES * CH) - (char*)d_ws);
    bool overlap = (ws_size >= need);

    const int FGA = GB + NHS * 8;            // 391 + 1600 (gemm half A + hist)
    const int FGB = GB + NSLICE * 8;         // 391 + 3200 (gemm half B + scatter)

    // prep (zero cnt + dtype detect + W split/transpose)
    prep_kernel<<<ZB + 256, 256, 0, stream>>>(eidx, flag, cnt,
                                              W1l, W1r, W2l, W2r, wbuf);

    // GEMM half A with histogram passenger
    gemm1a_hist<<<FGA, 512, 0, stream>>>(x, w1lh, w1ll, w1rh, w1rl,
                                         b1l, b1r, xlb, xr, NODES,
                                         eidx, flag, cnt);

    // CSR prefix
    scan1_kernel<<<NBLK, 256, 0, stream>>>(cnt, bsum);
    scan3_kernel<<<NBLK, 256, 0, stream>>>(cnt, bsum, offs, cursor);

    // GEMM half B with scatter passenger
    gemm1b_scatter<<<FGB, 512, 0, stream>>>(x, w1lh, w1ll, w1rh, w1rl,
                                            b1l, b1r, xlb, xr, NODES,
                                            eidx, flag, cursor, srcs);

    if (overlap) {
        // np1a: layer-1 node pass, nodes [0, HROWS)
        node_pass<4, true, true><<<HROWS / 4, 256, 0, stream>>>(
            xlb, xr, att1, bias1, offs, srcs, nullptr, hbh, hbl);
        // overlap: gemm_pl half A (rows [0,HROWS): hbh/hbl -> xlb2, xr)
        //       ∥ np1b (nodes [HROWS,NODES): xlb1 -> hbh/hbl rows >= HROWS).
        // Disjoint: gemm writes xlb2 (new buffer) + xr rows < HROWS; np1b
        // reads xlb1 + xr rows >= HROWS, writes hbh/hbl rows >= HROWS while
        // gemm reads hbh/hbl rows < HROWS (written by np1a, done).
        np1b_gplA<<<GB + NPB, 512, 0, stream>>>(
            hbh, hbl, w2lh, w2ll, w2rh, w2rl, b2l, b2r, xlb2, xr,
            xlb, att1, bias1, offs, srcs);
        // gemm_pl half B (rows [HROWS, NODES))
        gemm_pl_kernel<<<GB, 512, 0, stream>>>(hbh, hbl, w2lh, w2ll, w2rh, w2rl,
                                               b2l, b2r, xlb2, xr, NODES, HROWS);
        // layer-2 node pass (full)
        node_pass<1, false, false><<<(NODES + 3) / 4, 256, 0, stream>>>(
            xlb2, xr, att2, bias2, offs, srcs, out, nullptr, nullptr);
    } else {
        // serial fallback (proven R10 path; xlb reused for layer 2)
        node_pass<4, true, true><<<(NODES + 3) / 4, 256, 0, stream>>>(
            xlb, xr, att1, bias1, offs, srcs, nullptr, hbh, hbl);
        gemm_pl_kernel<<<GGC, 512, 0, stream>>>(hbh, hbl, w2lh, w2ll, w2rh, w2rl,
                                                b2l, b2r, xlb, xr, NODES, 0);
        node_pass<1, false, false><<<(NODES + 3) / 4, 256, 0, stream>>>(
            xlb, xr, att2, bias2, offs, srcs, out, nullptr, nullptr);
    }
}

// Round 12
// 320.656 us; speedup vs baseline: 1.0434x; 1.0434x over previous
//
#include <hip/hip_runtime.h>
#include <hip/hip_bf16.h>

#define NODES 50000
#define NEDGE 800000
#define CH 128          // all of IN/HID/OUT
#define NEG_SLOPE 0.2f
#define SCAN_CHUNK 2048
#define NBLK ((NODES + SCAN_CHUNK - 1) / SCAN_CHUNK)   // 25
#define NINF -1.0e30f
#define LOG2E 1.44269504088896340736f
#define RESCALE_THR 8.0f
#define NSLICE 400
#define SSLICE (NEDGE / NSLICE)       // 2000 edges per slice (scatter, 512 thr)
#define HSLICE 4000                   // edges per slice (hist, 512 thr)
#define NHS (NEDGE / HSLICE)          // 200 hist slices
#define ZB ((NODES + 255) / 256)      // 196 zero-blocks
#define GR 64
#define GGC ((NODES + GR - 1) / GR)   // 782 full-gemm blocks (layer 2)
#define GB 391                        // blocks per half-GEMM (layer 1)
#define HROWS (GB * GR)               // 25024 rows in half A
#define LDP 136   // padded row stride in shorts (272 B)

typedef short short8 __attribute__((ext_vector_type(8)));
typedef float f32x4 __attribute__((ext_vector_type(4)));
typedef float f32x2 __attribute__((ext_vector_type(2)));

__device__ __forceinline__ unsigned fbits(float f) {
    union { float f; unsigned u; } v; v.f = f; return v.u;
}
__device__ __forceinline__ float asf(unsigned u) {
    union { float f; unsigned u; } v; v.u = u; return v.f;
}
// fp32 -> bf16 (RNE)
__device__ __forceinline__ unsigned short f2bf(float f) {
    unsigned u = fbits(f);
    unsigned r = u + 0x7fff + ((u >> 16) & 1);
    return (unsigned short)(r >> 16);
}
__device__ __forceinline__ float bf2f(unsigned short h) {
    return asf(((unsigned)h) << 16);
}
// 8 bf16 (as uint4) -> 4 x float2 (packed-math friendly)
__device__ __forceinline__ void bf8cvt2(uint4 u, f32x2* f) {
    f[0] = (f32x2){asf(u.x << 16), asf(u.x & 0xFFFF0000u)};
    f[1] = (f32x2){asf(u.y << 16), asf(u.y & 0xFFFF0000u)};
    f[2] = (f32x2){asf(u.z << 16), asf(u.z & 0xFFFF0000u)};
    f[3] = (f32x2){asf(u.w << 16), asf(u.w & 0xFFFF0000u)};
}
// dst-range set for XCD-partitioned CSR build
__device__ __forceinline__ int dset(int dst) {
    return (int)(((unsigned)dst * 8u) / 50000u);   // exact partition of [0,50000)
}

// ---------------------------------------------------------------------------
// prep: zero histogram + detect edge dtype + W->bf16 hi/lo transpose, fused.
// ---------------------------------------------------------------------------
__global__ __launch_bounds__(256) void prep_kernel(const void* idx, int* flag,
                                                   int* cnt,
                                                   const float* __restrict__ W0,
                                                   const float* __restrict__ W1,
                                                   const float* __restrict__ W2,
                                                   const float* __restrict__ W3,
                                                   unsigned short* __restrict__ wbase) {
    int b = (int)blockIdx.x;
    if (b < ZB) {
        int t = b * 256 + (int)threadIdx.x;
        if (t < NODES) cnt[t] = 0;
        if (b == 0 && threadIdx.x < 64) {
            const int* w = (const int*)idx;
            int nz = (w[2 * threadIdx.x + 1] != 0) ? 1 : 0;
            unsigned long long bal = __ballot(nz);
            if (threadIdx.x == 0) *flag = (bal == 0ull) ? 1 : 0;
        }
        return;
    }
    int wb = b - ZB;                               // 0..255
    int which = wb >> 6;
    const float* W = (which == 0) ? W0 : (which == 1) ? W1 : (which == 2) ? W2 : W3;
    unsigned short* hiT = wbase + (size_t)which * 32768;
    unsigned short* loT = hiT + 16384;
    int i = (wb & 63) * 256 + (int)threadIdx.x;    // 0..16383
    int k = i >> 7, n = i & 127;
    float f = W[i];
    unsigned short h = f2bf(f);
    unsigned short l = f2bf(f - bf2f(h));
    hiT[n * CH + k] = h;
    loT[n * CH + k] = l;
}

__global__ __launch_bounds__(256) void scan1_kernel(const int* __restrict__ cnt,
                                                    int* __restrict__ bsum) {
    int base = blockIdx.x * SCAN_CHUNK + (int)threadIdx.x * 8;
    int s = 0;
    #pragma unroll
    for (int k = 0; k < 8; ++k) {
        int i = base + k;
        s += (i < NODES) ? cnt[i] : 0;
    }
    #pragma unroll
    for (int m = 1; m < 64; m <<= 1) s += __shfl_xor(s, m);
    __shared__ int ws[4];
    if ((threadIdx.x & 63) == 0) ws[threadIdx.x >> 6] = s;
    __syncthreads();
    if (threadIdx.x == 0) bsum[blockIdx.x] = ws[0] + ws[1] + ws[2] + ws[3];
}

__global__ __launch_bounds__(256) void scan3_kernel(const int* __restrict__ cnt,
                                                    const int* __restrict__ bsum,
                                                    int* __restrict__ offs,
                                                    int* __restrict__ cursor) {
    int tid = (int)threadIdx.x;
    int bpre = 0;
    #pragma unroll
    for (int b = 0; b < NBLK; ++b) bpre += (b < (int)blockIdx.x) ? bsum[b] : 0;

    int base = blockIdx.x * SCAN_CHUNK + tid * 8;
    int v[8];
    int s = 0;
    #pragma unroll
    for (int k = 0; k < 8; ++k) {
        int i = base + k;
        v[k] = (i < NODES) ? cnt[i] : 0;
        s += v[k];
    }
    int lane = tid & 63;
    int incl = s;
    #pragma unroll
    for (int m = 1; m < 64; m <<= 1) {
        int t = __shfl_up(incl, m);
        if (lane >= m) incl += t;
    }
    __shared__ int wtot[4];
    if (lane == 63) wtot[tid >> 6] = incl;
    __syncthreads();
    int w = tid >> 6;
    int wbase = 0;
    #pragma unroll
    for (int k = 0; k < 4; ++k) wbase += (k < w) ? wtot[k] : 0;
    int excl = bpre + wbase + (incl - s);
    #pragma unroll
    for (int k = 0; k < 8; ++k) {
        int i = base + k;
        if (i < NODES) { offs[i] = excl; cursor[i] = excl; }
        excl += v[k];
    }
    if (blockIdx.x == 0 && tid == 0) offs[NODES] = NEDGE;
}

// ---------------------------------------------------------------------------
// Shared layer-1 GEMM role body (R2 form, unchanged math): computes rows
// [r0, r0+64) of Ylb = bf16(X@Wl+bl), Yr = X@Wr+br via split-bf16 MFMA.
// ---------------------------------------------------------------------------
__device__ __forceinline__ void gemm1_role(
        int r0, int tid,
        unsigned short (*xh)[LDP], unsigned short (*xlo)[LDP],
        const float* __restrict__ X,
        const unsigned short* __restrict__ whTl, const unsigned short* __restrict__ wlTl,
        const unsigned short* __restrict__ whTr, const unsigned short* __restrict__ wlTr,
        const float* __restrict__ bl, const float* __restrict__ br,
        unsigned short* __restrict__ Ylb, float* __restrict__ Yr, int nrows) {
    // stage X tile: fp32 -> hi/lo bf16 (truncation split), packed
    {
        int row = tid >> 3;              // 0..63
        int c0 = (tid & 7) * 16;         // col start, 16 cols per thread
        const float* src = X + (size_t)(r0 + row) * CH + c0;
        bool valid = (r0 + row) < nrows;
        #pragma unroll
        for (int j = 0; j < 16; j += 4) {
            float4 v = valid ? *(const float4*)(src + j)
                             : make_float4(0.f, 0.f, 0.f, 0.f);
            unsigned ux = fbits(v.x), uy = fbits(v.y);
            unsigned uz = fbits(v.z), uw = fbits(v.w);
            unsigned hx = ux & 0xFFFF0000u, hy = uy & 0xFFFF0000u;
            unsigned hz = uz & 0xFFFF0000u, hw = uw & 0xFFFF0000u;
            uint2 hp;
            hp.x = (ux >> 16) | hy;
            hp.y = (uz >> 16) | hw;
            float lx = v.x - asf(hx), ly = v.y - asf(hy);
            float lz = v.z - asf(hz), lw = v.w - asf(hw);
            uint2 lp;
            lp.x = (fbits(lx) >> 16) | (fbits(ly) & 0xFFFF0000u);
            lp.y = (fbits(lz) >> 16) | (fbits(lw) & 0xFFFF0000u);
            *(uint2*)&xh[row][c0 + j]  = hp;
            *(uint2*)&xlo[row][c0 + j] = lp;
        }
    }
    __syncthreads();

    int wave = tid >> 6;      // 0..7: n-eighth (32 cols each)
    int lane = tid & 63;
    int l15 = lane & 15, q = lane >> 4;

    f32x4 acc[4][2];
    #pragma unroll
    for (int mt = 0; mt < 4; ++mt)
        #pragma unroll
        for (int nt = 0; nt < 2; ++nt) acc[mt][nt] = (f32x4)0.f;

    const unsigned short* bhp[2];
    const unsigned short* blp_[2];
    int ncol[2];
    #pragma unroll
    for (int nt = 0; nt < 2; ++nt) {
        int n = (wave * 2 + nt) * 16 + l15;       // 0..255
        ncol[nt] = n;
        int nn = n & 127;
        bhp[nt]  = ((n < CH) ? whTl : whTr) + (size_t)nn * CH;
        blp_[nt] = ((n < CH) ? wlTl : wlTr) + (size_t)nn * CH;
    }

    for (int kt = 0; kt < 4; ++kt) {
        int kofs = kt * 32 + q * 8;
        short8 ah[4], al[4];
        #pragma unroll
        for (int mt = 0; mt < 4; ++mt) {
            ah[mt] = *(const short8*)&xh[mt * 16 + l15][kofs];
            al[mt] = *(const short8*)&xlo[mt * 16 + l15][kofs];
        }
        #pragma unroll
        for (int nt = 0; nt < 2; ++nt) {
            short8 bh8 = *(const short8*)(bhp[nt] + kofs);
            short8 bl8 = *(const short8*)(blp_[nt] + kofs);
            #pragma unroll
            for (int mt = 0; mt < 4; ++mt) {
                acc[mt][nt] = __builtin_amdgcn_mfma_f32_16x16x32_bf16(
                                  ah[mt], bh8, acc[mt][nt], 0, 0, 0);
                acc[mt][nt] = __builtin_amdgcn_mfma_f32_16x16x32_bf16(
                                  al[mt], bh8, acc[mt][nt], 0, 0, 0);
                acc[mt][nt] = __builtin_amdgcn_mfma_f32_16x16x32_bf16(
                                  ah[mt], bl8, acc[mt][nt], 0, 0, 0);
            }
        }
    }

    // epilogue: C/D layout col=lane&15, row=q*4+reg
    #pragma unroll
    for (int nt = 0; nt < 2; ++nt) {
        int n = ncol[nt];
        int nc = n & 127;
        if (n < CH) {
            float bv = bl[nc];
            #pragma unroll
            for (int mt = 0; mt < 4; ++mt)
                #pragma unroll
                for (int reg = 0; reg < 4; ++reg) {
                    int row = r0 + mt * 16 + q * 4 + reg;
                    if (row < nrows)
                        Ylb[(size_t)row * CH + nc] = f2bf(acc[mt][nt][reg] + bv);
                }
        } else {
            float bv = br[nc];
            #pragma unroll
            for (int mt = 0; mt < 4; ++mt)
                #pragma unroll
                for (int reg = 0; reg < 4; ++reg) {
                    int row = r0 + mt * 16 + q * 4 + reg;
                    if (row < nrows)
                        Yr[(size_t)row * CH + nc] = acc[mt][nt][reg] + bv;
                }
        }
    }
}

// ---------------------------------------------------------------------------
// Fused kernel A: GEMM half A (rows [0, HROWS)) + edge HISTOGRAM passenger.
// hist only needs prep's zeroed cnt, so it rides under half the GEMM while
// the CSR scans wait. set = blockIdx&7: any 8 consecutive blockIdx cover all
// 8 sets per slice (XCD affinity preserved under round-robin dispatch).
// ---------------------------------------------------------------------------
__global__ __launch_bounds__(512) void gemm1a_hist(
        const float* __restrict__ X,
        const unsigned short* __restrict__ whTl, const unsigned short* __restrict__ wlTl,
        const unsigned short* __restrict__ whTr, const unsigned short* __restrict__ wlTr,
        const float* __restrict__ bl, const float* __restrict__ br,
        unsigned short* __restrict__ Ylb, float* __restrict__ Yr, int nrows,
        const void* idx, const int* flag, int* cnt) {
    __shared__ unsigned short xh[GR][LDP];
    __shared__ unsigned short xlo[GR][LDP];

    if (blockIdx.x >= GB) {
        // ---- histogram role: 200 slices x 4000 edges, 512 threads ----
        int set = (int)blockIdx.x & 7;
        int slice = ((int)blockIdx.x - GB) >> 3;    // 0..NHS-1
        int base = slice * HSLICE;
        int endE = base + HSLICE;
        int i64 = *flag;
        const int* w = (const int*)idx;
        for (int e = base + (int)threadIdx.x; e < endE; e += 512) {
            int dst = i64 ? w[2 * (NEDGE + e)] : w[NEDGE + e];
            if (dset(dst) == set) atomicAdd(&cnt[dst], 1);
        }
        return;
    }
    gemm1_role(blockIdx.x * GR, (int)threadIdx.x, xh, xlo,
               X, whTl, wlTl, whTr, wlTr, bl, br, Ylb, Yr, nrows);
}

// ---------------------------------------------------------------------------
// Fused kernel B: GEMM half B (rows [HROWS, NODES)) + edge SCATTER passenger
// (needs scan3's cursor). Same set/slice decomposition as A.
// ---------------------------------------------------------------------------
__global__ __launch_bounds__(512) void gemm1b_scatter(
        const float* __restrict__ X,
        const unsigned short* __restrict__ whTl, const unsigned short* __restrict__ wlTl,
        const unsigned short* __restrict__ whTr, const unsigned short* __restrict__ wlTr,
        const float* __restrict__ bl, const float* __restrict__ br,
        unsigned short* __restrict__ Ylb, float* __restrict__ Yr, int nrows,
        const void* idx, const int* flag, int* cursor, int* __restrict__ srcs) {
    __shared__ unsigned short xh[GR][LDP];
    __shared__ unsigned short xlo[GR][LDP];

    if (blockIdx.x >= GB) {
        // ---- scatter role: 400 slices x 2000 edges, 512 threads ----
        int set = (int)blockIdx.x & 7;
        int slice = ((int)blockIdx.x - GB) >> 3;    // 0..NSLICE-1
        int base = slice * SSLICE;
        int endE = base + SSLICE;
        int i64 = *flag;
        const int* w = (const int*)idx;
        for (int e = base + (int)threadIdx.x; e < endE; e += 512) {
            int dst = i64 ? w[2 * (NEDGE + e)] : w[NEDGE + e];
            if (dset(dst) == set) {
                int src = i64 ? w[2 * e] : w[e];
                int pos = atomicAdd(&cursor[dst], 1);
                srcs[pos] = src;
            }
        }
        return;
    }
    gemm1_role(HROWS + blockIdx.x * GR, (int)threadIdx.x, xh, xlo,
               X, whTl, wlTl, whTr, wlTr, bl, br, Ylb, Yr, nrows);
}

// ---------------------------------------------------------------------------
// Layer-2 GEMM (input pre-split as bf16 hi/lo planes): LDS-staged, 512 threads.
// ---------------------------------------------------------------------------
__global__ __launch_bounds__(512) void gemm_dual_mfma_pl(
        const unsigned short* __restrict__ Ah, const unsigned short* __restrict__ Al,
        const unsigned short* __restrict__ whTl, const unsigned short* __restrict__ wlTl,
        const unsigned short* __restrict__ whTr, const unsigned short* __restrict__ wlTr,
        const float* __restrict__ bl, const float* __restrict__ br,
        unsigned short* __restrict__ Ylb, float* __restrict__ Yr, int nrows) {
    __shared__ unsigned short xh[GR][LDP];
    __shared__ unsigned short xlo[GR][LDP];

    int r0 = blockIdx.x * GR;
    int tid = (int)threadIdx.x;

    // ---- stage hi/lo planes: coalesced 8 threads/row x 32B each ----
    {
        int row = tid >> 3;              // 0..63
        int c0 = (tid & 7) * 16;         // 16 u16 per thread
        int gr = r0 + row;
        if (gr > nrows - 1) gr = nrows - 1;   // clamp: dup row, stores guarded
        const uint4* ph = (const uint4*)(Ah + (size_t)gr * CH + c0);
        const uint4* pl = (const uint4*)(Al + (size_t)gr * CH + c0);
        uint4 h0 = ph[0], h1 = ph[1];
        uint4 l0 = pl[0], l1 = pl[1];
        *(uint4*)&xh[row][c0]      = h0;
        *(uint4*)&xh[row][c0 + 8]  = h1;
        *(uint4*)&xlo[row][c0]     = l0;
        *(uint4*)&xlo[row][c0 + 8] = l1;
    }
    __syncthreads();

    int wave = tid >> 6;      // 0..7
    int lane = tid & 63;
    int l15 = lane & 15, q = lane >> 4;

    f32x4 acc[4][2];
    #pragma unroll
    for (int mt = 0; mt < 4; ++mt)
        #pragma unroll
        for (int nt = 0; nt < 2; ++nt) acc[mt][nt] = (f32x4)0.f;

    const unsigned short* bhp[2];
    const unsigned short* blp_[2];
    int ncol[2];
    #pragma unroll
    for (int nt = 0; nt < 2; ++nt) {
        int n = (wave * 2 + nt) * 16 + l15;
        ncol[nt] = n;
        int nn = n & 127;
        bhp[nt]  = ((n < CH) ? whTl : whTr) + (size_t)nn * CH;
        blp_[nt] = ((n < CH) ? wlTl : wlTr) + (size_t)nn * CH;
    }

    for (int kt = 0; kt < 4; ++kt) {
        int kofs = kt * 32 + q * 8;
        short8 ah[4], al[4];
        #pragma unroll
        for (int mt = 0; mt < 4; ++mt) {
            ah[mt] = *(const short8*)&xh[mt * 16 + l15][kofs];
            al[mt] = *(const short8*)&xlo[mt * 16 + l15][kofs];
        }
        #pragma unroll
        for (int nt = 0; nt < 2; ++nt) {
            short8 bh8 = *(const short8*)(bhp[nt] + kofs);
            short8 bl8 = *(const short8*)(blp_[nt] + kofs);
            #pragma unroll
            for (int mt = 0; mt < 4; ++mt) {
                acc[mt][nt] = __builtin_amdgcn_mfma_f32_16x16x32_bf16(
                                  ah[mt], bh8, acc[mt][nt], 0, 0, 0);
                acc[mt][nt] = __builtin_amdgcn_mfma_f32_16x16x32_bf16(
                                  al[mt], bh8, acc[mt][nt], 0, 0, 0);
                acc[mt][nt] = __builtin_amdgcn_mfma_f32_16x16x32_bf16(
                                  ah[mt], bl8, acc[mt][nt], 0, 0, 0);
            }
        }
    }

    #pragma unroll
    for (int nt = 0; nt < 2; ++nt) {
        int n = ncol[nt];
        int nc = n & 127;
        if (n < CH) {
            float bv = bl[nc];
            #pragma unroll
            for (int mt = 0; mt < 4; ++mt)
                #pragma unroll
                for (int reg = 0; reg < 4; ++reg) {
                    int row = r0 + mt * 16 + q * 4 + reg;
                    if (row < nrows)
                        Ylb[(size_t)row * CH + nc] = f2bf(acc[mt][nt][reg] + bv);
                }
        } else {
            float bv = br[nc];
            #pragma unroll
            for (int mt = 0; mt < 4; ++mt)
                #pragma unroll
                for (int reg = 0; reg < 4; ++reg) {
                    int row = r0 + mt * 16 + q * 4 + reg;
                    if (row < nrows)
                        Yr[(size_t)row * CH + nc] = acc[mt][nt][reg] + bv;
                }
        }
    }
}

// ---------------------------------------------------------------------------
// Fused GATv2 edge pass (R2 form, best measured): one node per wave, 16 lanes
// per edge row, 4 edges in flight (one per quarter-wave). Defer-max online
// softmax (T13).
// SPLITOUT: write output as trunc-split bf16 hi/lo planes (layer-1 -> gemm2).
// ---------------------------------------------------------------------------
template <int HEADS, bool RELU, bool SPLITOUT>
__global__ __launch_bounds__(256) void node_pass(
        const unsigned short* __restrict__ xlb,   // [N][128] bf16 bits
        const float* __restrict__ xr,
        const float* __restrict__ att,    // 128 floats, flat (H, C/H)
        const float* __restrict__ bias,   // 128 floats
        const int* __restrict__ offs, const int* __restrict__ srcs,
        float* __restrict__ outf,
        unsigned short* __restrict__ outh, unsigned short* __restrict__ outl) {
    constexpr int GL = (CH / HEADS) / 8;     // lanes per head group: 4 or 16
    int wave = (int)threadIdx.x >> 6;
    int i = blockIdx.x * 4 + wave;
    int lane = (int)threadIdx.x & 63;
    int g = lane >> 4;                       // quarter 0..3
    int l16 = lane & 15;
    int c0 = l16 * 8;                        // this lane's 8 channels

    f32x2 r2[4], a2[4], s2[4];
    {
        const float4* xrp = (const float4*)(xr + (size_t)i * CH + c0);
        float4 r0 = xrp[0], r1 = xrp[1];
        r2[0] = (f32x2){r0.x, r0.y}; r2[1] = (f32x2){r0.z, r0.w};
        r2[2] = (f32x2){r1.x, r1.y}; r2[3] = (f32x2){r1.z, r1.w};
        const float4* atp = (const float4*)(att + c0);
        float4 a0 = atp[0], a1 = atp[1];
        a2[0] = (f32x2){a0.x, a0.y} * LOG2E; a2[1] = (f32x2){a0.z, a0.w} * LOG2E;
        a2[2] = (f32x2){a1.x, a1.y} * LOG2E; a2[3] = (f32x2){a1.z, a1.w} * LOG2E;
    }
    // self row (bf16)
    uint4 us = *(const uint4*)(xlb + (size_t)i * CH + c0);
    bf8cvt2(us, s2);

    f32x2 td = (f32x2)0.f;
    #pragma unroll
    for (int k = 0; k < 4; ++k) {
        f32x2 z = s2[k] + r2[k];
        f32x2 l = __builtin_elementwise_max(z, z * NEG_SLOPE);
        td += l * a2[k];
    }
    float ts = td.x + td.y;
    #pragma unroll
    for (int msk = 1; msk < GL; msk <<= 1) ts += __shfl_xor(ts, msk);

    // defer-max init: every quarter anchors at the self logit (finite, and
    // identical across quarters since all quarters load the same self row).
    float m = ts;
    float d = (g == 0) ? 1.f : 0.f;
    f32x2 acc2[4];
    #pragma unroll
    for (int k = 0; k < 4; ++k) acc2[k] = (g == 0) ? s2[k] : (f32x2)0.f;

    int beg = offs[i], end = offs[i + 1];
    int deg = end - beg;
    int iters = (deg + 3) >> 2;
    if (iters > 0) {
        int last = end - 1;
        int e = beg + g;
        int si = srcs[min(e, last)];
        uint4 u = *(const uint4*)(xlb + (size_t)si * CH + c0);

        for (int it = 0; it < iters; ++it, e += 4) {
            bool valid = e < end;
            // prefetch next edge for this quarter (clamped: own segment only)
            int sn = srcs[min(e + 4, last)];
            uint4 un = *(const uint4*)(xlb + (size_t)sn * CH + c0);

            f32x2 f2[4];
            bf8cvt2(u, f2);
            f32x2 td2 = (f32x2)0.f;
            #pragma unroll
            for (int k = 0; k < 4; ++k) {
                f32x2 z = f2[k] + r2[k];
                f32x2 l = __builtin_elementwise_max(z, z * NEG_SLOPE);
                td2 += l * a2[k];
            }
            float t = td2.x + td2.y;
            #pragma unroll
            for (int msk = 1; msk < GL; msk <<= 1) t += __shfl_xor(t, msk);
            t = valid ? t : NINF;   // exp2(NINF - m) underflows to 0 in HW

            if (__any(t > m + RESCALE_THR)) {
                // exact rescale path (rare)
                float nm = fmaxf(m, t);
                float sc = exp2f(m - nm);
                float p  = exp2f(t - nm);
                d = d * sc + p;
                #pragma unroll
                for (int k = 0; k < 4; ++k) acc2[k] = acc2[k] * sc + f2[k] * p;
                m = nm;
            } else {
                // deferred path: p <= 2^THR, no rescale of the accumulator
                float p = exp2f(t - m);
                d += p;
                #pragma unroll
                for (int k = 0; k < 4; ++k) acc2[k] += f2[k] * p;
            }
            u = un;
        }
    }

    // merge the 4 quarter-wave states (butterfly: all lanes converge)
    #pragma unroll
    for (int msk = 16; msk <= 32; msk <<= 1) {
        float mo  = __shfl_xor(m, msk);
        float dof = __shfl_xor(d, msk);
        float nm = fmaxf(m, mo);
        float s0 = exp2f(m - nm), s1 = exp2f(mo - nm);
        d = d * s0 + dof * s1;
        #pragma unroll
        for (int k = 0; k < 4; ++k) {
            f32x2 ao;
            ao.x = __shfl_xor(acc2[k].x, msk);
            ao.y = __shfl_xor(acc2[k].y, msk);
            acc2[k] = acc2[k] * s0 + ao * s1;
        }
        m = nm;
    }

    if (g == 0) {
        float inv = 1.0f / d;
        const float4* bp = (const float4*)(bias + c0);
        float4 b0 = bp[0], b1 = bp[1];
        float bb[8] = {b0.x, b0.y, b0.z, b0.w, b1.x, b1.y, b1.z, b1.w};
        float o[8];
        #pragma unroll
        for (int k = 0; k < 4; ++k) {
            o[2*k]   = acc2[k].x * inv + bb[2*k];
            o[2*k+1] = acc2[k].y * inv + bb[2*k+1];
        }
        #pragma unroll
        for (int c = 0; c < 8; ++c)
            if (RELU) o[c] = fmaxf(o[c], 0.f);
        if (SPLITOUT) {
            unsigned hu[8];
            float lo[8];
            #pragma unroll
            for (int c = 0; c < 8; ++c) {
                hu[c] = fbits(o[c]) & 0xFFFF0000u;
                lo[c] = o[c] - asf(hu[c]);
            }
            uint4 ph, pl;
            ph.x = (hu[0] >> 16) | hu[1];  ph.y = (hu[2] >> 16) | hu[3];
            ph.z = (hu[4] >> 16) | hu[5];  ph.w = (hu[6] >> 16) | hu[7];
            pl.x = (fbits(lo[0]) >> 16) | (fbits(lo[1]) & 0xFFFF0000u);
            pl.y = (fbits(lo[2]) >> 16) | (fbits(lo[3]) & 0xFFFF0000u);
            pl.z = (fbits(lo[4]) >> 16) | (fbits(lo[5]) & 0xFFFF0000u);
            pl.w = (fbits(lo[6]) >> 16) | (fbits(lo[7]) & 0xFFFF0000u);
            *(uint4*)(outh + (size_t)i * CH + c0) = ph;
            *(uint4*)(outl + (size_t)i * CH + c0) = pl;
        } else {
            float4 w0 = make_float4(o[0], o[1], o[2], o[3]);
            float4 w1 = make_float4(o[4], o[5], o[6], o[7]);
            float4* op = (float4*)(outf + (size_t)i * CH + c0);
            op[0] = w0; op[1] = w1;
        }
    }
}

// ---------------------------------------------------------------------------
extern "C" void kernel_launch(void* const* d_in, const int* in_sizes, int n_in,
                              void* d_out, int out_size, void* d_ws, size_t ws_size,
                              hipStream_t stream) {
    const float* x     = (const float*)d_in[0];
    const void*  eidx  = d_in[1];
    const float* W1l   = (const float*)d_in[2];
    const float* b1l   = (const float*)d_in[3];
    const float* W1r   = (const float*)d_in[4];
    const float* b1r   = (const float*)d_in[5];
    const float* att1  = (const float*)d_in[6];
    const float* bias1 = (const float*)d_in[7];
    const float* W2l   = (const float*)d_in[8];
    const float* b2l   = (const float*)d_in[9];
    const float* W2r   = (const float*)d_in[10];
    const float* b2r   = (const float*)d_in[11];
    const float* att2  = (const float*)d_in[12];
    const float* bias2 = (const float*)d_in[13];
    float* out = (float*)d_out;

    // workspace layout
    unsigned short* xlb = (unsigned short*)d_ws;        // N*128 bf16 (attn side)
    float* xr = (float*)(xlb + (size_t)NODES * CH);     // N*128 fp32 (dst side)
    unsigned short* hbh = (unsigned short*)(xr + (size_t)NODES * CH); // N*128 u16
    unsigned short* hbl = hbh + (size_t)NODES * CH;     // N*128 u16
    int* offs   = (int*)(hbl + (size_t)NODES * CH);     // N+1
    int* cnt    = offs + (NODES + 1);                   // N
    int* cursor = cnt + NODES;                          // N
    int* srcs   = cursor + NODES;                       // E
    int* flag   = srcs + NEDGE;                         // 1
    int* bsum   = flag + 1;                             // NBLK
    unsigned short* wbuf =
        (unsigned short*)(((uintptr_t)(bsum + NBLK) + 15) & ~(uintptr_t)15);
    unsigned short* w1lh = wbuf;              unsigned short* w1ll = wbuf + 16384;
    unsigned short* w1rh = wbuf + 32768;      unsigned short* w1rl = wbuf + 49152;
    unsigned short* w2lh = wbuf + 65536;      unsigned short* w2ll = wbuf + 81920;
    unsigned short* w2rh = wbuf + 98304;      unsigned short* w2rl = wbuf + 114688;

    const int FGA = GB + NHS * 8;            // 391 + 1600 (gemm half A + hist)
    const int FGB = GB + NSLICE * 8;         // 391 + 3200 (gemm half B + scatter)

    // prep (zero cnt + dtype detect + W split/transpose)
    prep_kernel<<<ZB + 256, 256, 0, stream>>>(eidx, flag, cnt,
                                              W1l, W1r, W2l, W2r, wbuf);

    // GEMM half A with histogram passenger (hist only needs zeroed cnt)
    gemm1a_hist<<<FGA, 512, 0, stream>>>(x, w1lh, w1ll, w1rh, w1rl,
                                         b1l, b1r, xlb, xr, NODES,
                                         eidx, flag, cnt);

    // CSR prefix
    scan1_kernel<<<NBLK, 256, 0, stream>>>(cnt, bsum);
    scan3_kernel<<<NBLK, 256, 0, stream>>>(cnt, bsum, offs, cursor);

    // GEMM half B with scatter passenger (needs scan3's cursor)
    gemm1b_scatter<<<FGB, 512, 0, stream>>>(x, w1lh, w1ll, w1rh, w1rl,
                                            b1l, b1r, xlb, xr, NODES,
                                            eidx, flag, cursor, srcs);

    // layer-1 edge pass
    node_pass<4, true, true><<<(NODES + 3) / 4, 256, 0, stream>>>(
        xlb, xr, att1, bias1, offs, srcs, nullptr, hbh, hbl);

    // layer 2 (in-place xlb overwrite keeps np2's gather buffer cache-warm)
    gemm_dual_mfma_pl<<<GGC, 512, 0, stream>>>(hbh, hbl, w2lh, w2ll, w2rh, w2rl,
                                               b2l, b2r, xlb, xr, NODES);
    node_pass<1, false, false><<<(NODES + 3) / 4, 256, 0, stream>>>(
        xlb, xr, att2, bias2, offs, srcs, out, nullptr, nullptr);
}